// Round 11
// baseline (1644.953 us; speedup 1.0000x reference)
//
#include <hip/hip_runtime.h>
#include <hip/hip_bf16.h>
#include <math.h>

// T=128, B=32, D=512, H=512, N=64, A=32, TAU=1
#define NTHR  512
#define NBLK  256              // 32 BC blocks + 224 GEMM blocks (all CUs)
#define HTXS  18432            // hTx stride per t: 32 batches x 576 (b-major)

// ---- flag area (int offsets into d_ws), LINE-SPACED (r1/r6-proven best) ----
// hflag[b] = bar[b*32]           (BC b sc1-stores t+1; own 128B line)
// wflag[g] = bar[1024 + g*32]    (GEMM block g sc1-stores t+1)
//   g<64    "crit": cols [16*(g>>1),+16)  fp32 K=576 (th path -> argmax)
//   64..127 "def":  cols [512+32*((g-64)>>1),+32) fp32 K=512 (vA/vB)
//   128..223 "late": cols [1536+64*((g-128)>>1),+64) bf16 K=512
// r11 = r7 (best, 1246us) + ONE isolated change: def K=576->512
// (Wcat rows 512:576 are ZERO for cols>=512 — skipping is exact; r7
// computed them).  r10's wait-split REVERTED: it cost ~60us steady-state
// and produced a 32ms outlier dispatch (3-stage polling hazard).
// r9 lessons: crit stays 16-col/288-FMA (argmax chain binds); late tile
// stays 4-col ushort4.  r8: no work before a producer's flag.
#define OFF_HTX  8192                       // hTx_all: [129][32][576]
#define OFF_OC   (OFF_HTX + 129*HTXS)       // oc: [32][4608]
#define OFF_HNEW (OFF_OC + 32*4608)         // hnew_part: [32][64][512]
#define OFF_WHH  (OFF_HNEW + 32*64*512)     // whh_part: [32][64][1536]
#define OFF_C0   (OFF_WHH + 32*64*1536)     // c0: [1536]
#define OFF_WCAT (OFF_C0 + 1536)            // Wcat: [576][4608] fp32 row-major
#define OFF_WB16 (OFF_WCAT + 576*4608)      // Wb16: [512][3072] bf16 (ushort)
#define OFF_P1   (OFF_WB16 + 512*1536)      // P1: [4096][1536]
#define OFF_P2   (OFF_P1 + 4096*1536)       // P2: [4096][512]
// end ≈ 74.2 MB (< 76.5 MB known-good)

// sc1 (agent-scope): bypass per-XCD L2, coherent at LLC. Flags, oc, hTx
// writes are sc1; hTx READS are normal cached loads (rotating buffers).
__device__ __forceinline__ float cohLoad(const float* p) {
  return __hip_atomic_load(p, __ATOMIC_RELAXED, __HIP_MEMORY_SCOPE_AGENT);
}
__device__ __forceinline__ void cohStore(float* p, float v) {
  __hip_atomic_store(p, v, __ATOMIC_RELAXED, __HIP_MEMORY_SCOPE_AGENT);
}
__device__ __forceinline__ int cohLoadI(const int* p) {
  return __hip_atomic_load(p, __ATOMIC_RELAXED, __HIP_MEMORY_SCOPE_AGENT);
}
__device__ __forceinline__ void cohStoreI(int* p, int v) {
  __hip_atomic_store(p, v, __ATOMIC_RELAXED, __HIP_MEMORY_SCOPE_AGENT);
}
__device__ __forceinline__ float bf2f(unsigned short u) {
  return __uint_as_float(((unsigned int)u) << 16);
}

// ---------------------------------------------------------------------------
// Generic tiled fp32 GEMM (pre-pass only)
// ---------------------------------------------------------------------------
__global__ __launch_bounds__(256) void gemm_f32(
    const float* __restrict__ A, const float* __restrict__ B,
    const float* __restrict__ bias, float* __restrict__ C,
    int M, int N, int K, int lda, int ldb, int ldc)
{
  __shared__ float As[16][132];
  __shared__ float Bs[16][64];
  const int bm = blockIdx.x * 128, bn = blockIdx.y * 64;
  const int tid = threadIdx.x;
  const int tx = tid & 15, ty = tid >> 4;
  float acc[8][4];
  #pragma unroll
  for (int i = 0; i < 8; ++i)
    #pragma unroll
    for (int j = 0; j < 4; ++j) acc[i][j] = 0.f;

  for (int kt = 0; kt < K; kt += 16) {
    #pragma unroll
    for (int i = 0; i < 2; ++i) {
      int li = tid + i*256;
      int r = li >> 2, q = li & 3;
      float4 a4 = *(const float4*)(A + (size_t)(bm + r)*lda + kt + q*4);
      As[q*4+0][r] = a4.x; As[q*4+1][r] = a4.y;
      As[q*4+2][r] = a4.z; As[q*4+3][r] = a4.w;
    }
    {
      int k = tid >> 4, nq = tid & 15;
      *(float4*)(&Bs[k][nq*4]) = *(const float4*)(B + (size_t)(kt + k)*ldb + bn + nq*4);
    }
    __syncthreads();
    #pragma unroll
    for (int kk = 0; kk < 16; ++kk) {
      float av[8], bv[4];
      *(float4*)(av)   = *(const float4*)(&As[kk][ty*8]);
      *(float4*)(av+4) = *(const float4*)(&As[kk][ty*8+4]);
      *(float4*)(bv)   = *(const float4*)(&Bs[kk][tx*4]);
      #pragma unroll
      for (int i = 0; i < 8; ++i)
        #pragma unroll
        for (int j = 0; j < 4; ++j) acc[i][j] += av[i]*bv[j];
    }
    __syncthreads();
  }
  #pragma unroll
  for (int i = 0; i < 8; ++i) {
    int m = bm + ty*8 + i;
    #pragma unroll
    for (int j = 0; j < 4; ++j) {
      int n = bn + tx*4 + j;
      float v = acc[i][j];
      if (bias) v += bias[n];
      C[(size_t)m*ldc + n] = v;
    }
  }
}

// ---------------------------------------------------------------------------
// Setup: Wcat (row-major [576][4608]) static parts + c0.
// ---------------------------------------------------------------------------
__global__ __launch_bounds__(512) void setup_kernel(
    const float* __restrict__ W_hm, const float* __restrict__ fc2_w,
    const float* __restrict__ W_um, const float* __restrict__ W_hh,
    const float* __restrict__ bias, const float* __restrict__ fc2_b,
    float* __restrict__ Wcat, float* __restrict__ c0)
{
  const int idx = blockIdx.x * 512 + threadIdx.x;
  if (idx < 512*1536) {                       // rows 0:512, cols 0:1536
    int k = idx / 1536, c = idx % 1536;
    float v;
    if (c < 512)       v = W_hm[k*512 + c];
    else if (c < 1024) v = fc2_w[k*512 + (c-512)];
    else               v = fc2_w[(size_t)(512+k)*512 + (c-1024)];
    Wcat[(size_t)k*4608 + c] = v;
    return;
  }
  int i = idx - 512*1536;
  if (i < 64*4608) {                          // rows 512:576
    int k2 = i / 4608, c = i % 4608;
    Wcat[(size_t)(512+k2)*4608 + c] = (c < 512) ? W_um[k2*512 + c] : 0.f;
    return;
  }
  i -= 64*4608;
  if (i < 1536) {                             // c0 = fc2_b@W_hh + bias_hh
    float s = bias[1536 + i];
    for (int m = 0; m < 512; ++m) s += fc2_b[m] * W_hh[(size_t)m*1536 + i];
    c0[i] = s;
  }
}

// Wb16[k][3072] = bf16(Wcat[k][1536+c]), k<512 — runs after M_A/M_B GEMMs.
__global__ __launch_bounds__(512) void cvt_kernel(
    const float* __restrict__ Wcat, unsigned short* __restrict__ Wb16)
{
  const int idx = blockIdx.x * 512 + threadIdx.x;   // 512*3072
  const int k = idx / 3072, c = idx % 3072;
  __hip_bfloat16 h = __float2bfloat16(Wcat[(size_t)k*4608 + 1536 + c]);
  Wb16[idx] = *(unsigned short*)&h;
}

// ---------------------------------------------------------------------------
// Persistent scan. Blocks 0..31: BC (batch). Blocks 32..255: GEMM.
//   gb = bid-32, bg = gb&1 (batch half):
//     gb<64   crit: cols [cg*16,+16)        fp32 K=576 (16 segs x 36k)
//     gb<128  def:  cols [512+cg*32,+32)    fp32 K=512 (8 segs x 64k)
//     gb<224  late: cols [1536+cg*64,+64)   bf16 K=512 (8 segs x 64k)
// LDS hxs[16][580] b-major; wave w stages its own k-slice (no stage bar).
// Thread tile (s, c, bq=4 batches): 4 ds_read_b128 per 4k, weights
// amortized x4 batches (r1 economics, r7-proven).
// ---------------------------------------------------------------------------
__global__ __launch_bounds__(NTHR, 1) void persist_kernel(
    const float* __restrict__ P1, const float* __restrict__ P2,
    const float* __restrict__ Wcat, const unsigned short* __restrict__ Wb16,
    float* __restrict__ oc, float* __restrict__ hTx_all,
    float* __restrict__ hnew_part, float* __restrict__ whh_part,
    const float* __restrict__ c0, const float* __restrict__ fc1_w,
    const float* __restrict__ fc1_b, const float* __restrict__ fc2_b,
    const float* __restrict__ u_noise, const int* __restrict__ length,
    const float* __restrict__ fc_w, const float* __restrict__ fc_b,
    float* __restrict__ out, int* __restrict__ bar)
{
  __shared__ float smem[13696]; // hxs 16x580=9280 + red (crit 16x272=4352)
  const int bid = blockIdx.x;
  const int tid = threadIdx.x;

  if (bid >= 32) {
    // ================= GEMM blocks =================
    const int gb = bid - 32;             // 0..223
    const int bg = gb & 1;               // batch half
    const int wv = tid >> 6, lane = tid & 63;
    const int bq = tid & 3;              // batch quad: rows bq*4..+3
    float* hxs = smem;                   // [16][580] b-major

    if (gb < 64) {
      // ---- crit: cols [cg*16,+16), fp32 K=576, 16 segs x 36 ----
      const int cg = gb >> 1;
      const int colbase = cg * 16;
      const int s = tid >> 5;            // 0..15 (wave covers 2 segs)
      const int c = (tid >> 2) & 7;      // 2 cols each
      const int kbase = s * 36;
      const float* wbase = Wcat + (size_t)kbase*4608 + colbase + c*2;
      float* red = smem + 9280;          // [16][272]
      for (int t = 0; t < 128; ++t) {
        if (tid < 16) {
          while (cohLoadI(&bar[(bg*16 + tid)*32]) < t) __builtin_amdgcn_s_sleep(1);
        }
        __syncthreads();
        {  // wave-private stage: k-slice [wv*72,+72) of 16 rows = 288 f4
          const float* hsrc = hTx_all + (size_t)t*HTXS + (size_t)(bg*16)*576 + wv*72;
          float* hdst = hxs + wv*72;
          for (int i = lane; i < 288; i += 64) {
            int bb = i / 18, q = i - bb*18;
            *(float4*)(hdst + bb*580 + q*4) = *(const float4*)(hsrc + bb*576 + q*4);
          }
        }
        float acc[4][2] = {{0.f,0.f},{0.f,0.f},{0.f,0.f},{0.f,0.f}};
        const float* hp = hxs + (bq*4)*580 + kbase;
        #pragma unroll 3
        for (int it = 0; it < 9; ++it) {
          float ha[4][4];
          *(float4*)(&ha[0][0]) = *(const float4*)(hp + 0*580 + it*4);
          *(float4*)(&ha[1][0]) = *(const float4*)(hp + 1*580 + it*4);
          *(float4*)(&ha[2][0]) = *(const float4*)(hp + 2*580 + it*4);
          *(float4*)(&ha[3][0]) = *(const float4*)(hp + 3*580 + it*4);
          const float* wp = wbase + (size_t)(it*4)*4608;
          #pragma unroll
          for (int kk = 0; kk < 4; ++kk) {
            float w0 = wp[0], w1 = wp[1]; wp += 4608;
            #pragma unroll
            for (int j = 0; j < 4; ++j) {
              acc[j][0] += ha[j][kk]*w0;
              acc[j][1] += ha[j][kk]*w1;
            }
          }
        }
        {
          float* rp = red + s*272 + (bq*4)*16 + c*2;
          #pragma unroll
          for (int j = 0; j < 4; ++j)
            *(float2*)(rp + j*16) = make_float2(acc[j][0], acc[j][1]);
        }
        __syncthreads();
        if (tid < 256) {                 // 16b x 16c outputs
          float ssum = 0.f;
          #pragma unroll
          for (int w = 0; w < 16; ++w) ssum += red[w*272 + tid];
          int b16 = tid >> 4, cc = tid & 15;
          cohStore(&oc[(size_t)(bg*16 + b16)*4608 + colbase + cc], ssum);
        }
        __syncthreads();                 // drain sc1 stores
        if (tid == 0) cohStoreI(&bar[1024 + gb*32], t + 1);
      }
    } else if (gb < 128) {
      // ---- def: cols [512+cg*32,+32), fp32 K=512, 8 segs x 64 ----
      // (rows 512:576 of Wcat are zero for cols>=512 -> skipping is exact)
      const int cg = (gb - 64) >> 1;
      const int colbase = 512 + cg * 32;
      const int s = tid >> 6;            // 0..7 (= wave)
      const int c = (tid >> 2) & 15;     // 2 cols each
      const int kbase = s * 64;
      const float* wbase = Wcat + (size_t)kbase*4608 + colbase + c*2;
      float* red = smem + 9280;          // [8][520]
      for (int t = 0; t < 128; ++t) {
        if (tid < 16) {
          while (cohLoadI(&bar[(bg*16 + tid)*32]) < t) __builtin_amdgcn_s_sleep(1);
        }
        __syncthreads();
        {  // wave-private stage: k-slice [wv*64,+64) of 16 rows = 256 f4
          const float* hsrc = hTx_all + (size_t)t*HTXS + (size_t)(bg*16)*576 + wv*64;
          float* hdst = hxs + wv*64;
          for (int i = lane; i < 256; i += 64) {
            int bb = i >> 4, q = i & 15;
            *(float4*)(hdst + bb*580 + q*4) = *(const float4*)(hsrc + bb*576 + q*4);
          }
        }
        float acc[4][2] = {{0.f,0.f},{0.f,0.f},{0.f,0.f},{0.f,0.f}};
        const float* hp = hxs + (bq*4)*580 + kbase;
        #pragma unroll 4
        for (int it = 0; it < 16; ++it) {
          float ha[4][4];
          *(float4*)(&ha[0][0]) = *(const float4*)(hp + 0*580 + it*4);
          *(float4*)(&ha[1][0]) = *(const float4*)(hp + 1*580 + it*4);
          *(float4*)(&ha[2][0]) = *(const float4*)(hp + 2*580 + it*4);
          *(float4*)(&ha[3][0]) = *(const float4*)(hp + 3*580 + it*4);
          const float* wp = wbase + (size_t)(it*4)*4608;
          #pragma unroll
          for (int kk = 0; kk < 4; ++kk) {
            float w0 = wp[0], w1 = wp[1]; wp += 4608;
            #pragma unroll
            for (int j = 0; j < 4; ++j) {
              acc[j][0] += ha[j][kk]*w0;
              acc[j][1] += ha[j][kk]*w1;
            }
          }
        }
        {
          float* rp = red + s*520 + (bq*4)*32 + c*2;
          #pragma unroll
          for (int j = 0; j < 4; ++j)
            *(float2*)(rp + j*32) = make_float2(acc[j][0], acc[j][1]);
        }
        __syncthreads();
        {                                 // 16b x 32c, one per thread
          float ssum = 0.f;
          #pragma unroll
          for (int w = 0; w < 8; ++w) ssum += red[w*520 + tid];
          int b16 = tid >> 5, cc = tid & 31;
          cohStore(&oc[(size_t)(bg*16 + b16)*4608 + colbase + cc], ssum);
        }
        __syncthreads();                 // drain sc1 stores
        if (tid == 0) cohStoreI(&bar[1024 + gb*32], t + 1);
      }
    } else {
      // ---- late: cols [1536+cg*64,+64), bf16 K=512, 8 segs x 64 ----
      const int cg = (gb - 128) >> 1;
      const int colbase = 1536 + cg * 64;
      const int s = tid >> 6;            // 0..7 (= wave)
      const int c = (tid >> 2) & 15;     // 4 cols each
      const int kbase = s * 64;
      const unsigned short* wbase = Wb16 + (size_t)kbase*3072 + (colbase - 1536) + c*4;
      float* red = smem;                 // [8][1024] ALIASES hxs (barrier-fenced)
      for (int t = 0; t < 128; ++t) {
        if (tid < 16) {
          while (cohLoadI(&bar[(bg*16 + tid)*32]) < t) __builtin_amdgcn_s_sleep(1);
        }
        __syncthreads();
        {  // wave-private stage: k-slice [wv*64,+64) of 16 rows = 256 f4
          const float* hsrc = hTx_all + (size_t)t*HTXS + (size_t)(bg*16)*576 + wv*64;
          float* hdst = hxs + wv*64;
          for (int i = lane; i < 256; i += 64) {
            int bb = i >> 4, q = i & 15;
            *(float4*)(hdst + bb*580 + q*4) = *(const float4*)(hsrc + bb*576 + q*4);
          }
        }
        float acc[4][4] = {{0.f,0.f,0.f,0.f},{0.f,0.f,0.f,0.f},
                           {0.f,0.f,0.f,0.f},{0.f,0.f,0.f,0.f}};
        const float* hp = hxs + (bq*4)*580 + kbase;
        #pragma unroll 2
        for (int it = 0; it < 16; ++it) {
          float ha[4][4];
          *(float4*)(&ha[0][0]) = *(const float4*)(hp + 0*580 + it*4);
          *(float4*)(&ha[1][0]) = *(const float4*)(hp + 1*580 + it*4);
          *(float4*)(&ha[2][0]) = *(const float4*)(hp + 2*580 + it*4);
          *(float4*)(&ha[3][0]) = *(const float4*)(hp + 3*580 + it*4);
          #pragma unroll
          for (int kk = 0; kk < 4; ++kk) {
            const ushort4 u4 = *(const ushort4*)(wbase + (size_t)(it*4 + kk)*3072);
            float w0 = bf2f(u4.x), w1 = bf2f(u4.y), w2 = bf2f(u4.z), w3 = bf2f(u4.w);
            #pragma unroll
            for (int j = 0; j < 4; ++j) {
              float f = ha[j][kk];
              acc[j][0] += f*w0; acc[j][1] += f*w1;
              acc[j][2] += f*w2; acc[j][3] += f*w3;
            }
          }
        }
        __syncthreads();                 // all computes done before alias write
        {
          float* rp = red + s*1024 + (bq*4)*64 + c*4;
          #pragma unroll
          for (int j = 0; j < 4; ++j)
            *(float4*)(rp + j*64) = make_float4(acc[j][0], acc[j][1], acc[j][2], acc[j][3]);
        }
        __syncthreads();
        for (int i = tid; i < 1024; i += NTHR) {  // 16b x 64c
          float ssum = 0.f;
          #pragma unroll
          for (int w = 0; w < 8; ++w) ssum += red[w*1024 + i];
          int b16 = i >> 6, cc = i & 63;
          cohStore(&oc[(size_t)(bg*16 + b16)*4608 + colbase + cc], ssum);
        }
        __syncthreads();                 // drain sc1 stores
        if (tid == 0) cohStoreI(&bar[1024 + gb*32], t + 1);
      }
    }
  } else {
    // ================= BC block: batch b =================
    const int b = bid;
    const int lenb = length[b];
    float hcur = 0.f;
    float usage_r = -99999.f;            // valid for tid<64
    int jprev = 0;                       // thread-0 only
    int* flg = (int*)(smem + 1100);
    const float c0r = c0[tid], c0z = c0[512 + tid], c0n = c0[1024 + tid];
    const float fc2bv = fc2_b[tid];
    const float f1b = (tid < 64) ? fc1_b[tid] : 0.f;
    const int n_ = tid & 63, kg_ = tid >> 6;
    const float* fw = fc1_w + (size_t)kg_*64*64 + n_;

    for (int t = 0; t < 128; ++t) {
      const int t32b = t*32 + b;
      // prefetch step inputs (independent of flags)
      const float* p1p = P1 + (size_t)t32b*1536;
      float p1r = p1p[tid], p1z = p1p[512 + tid], p1n = p1p[1024 + tid];
      float p2v = P2[(size_t)t32b*512 + tid];
      float uval = (tid < 64) ? u_noise[(size_t)t32b*64 + tid] : 0.f;
      // ---- wait CRIT blocks (g 0..63): argmax chain ----
      if (tid < 64) {
        while (cohLoadI(&bar[1024 + tid*32]) < t + 1) __builtin_amdgcn_s_sleep(1);
      }
      __syncthreads();
      const float* ocb = oc + (size_t)b*4608;
      float oct = cohLoad(ocb + tid);
      smem[tid] = tanhf(p2v + oct);      // th
      __syncthreads();
      {                                  // fc1 partial dots
        float sdot = 0.f;
        #pragma unroll 8
        for (int k = 0; k < 64; ++k) sdot += smem[kg_*64 + k] * fw[(size_t)k*64];
        smem[512 + tid] = sdot;
      }
      __syncthreads();
      if (tid < 64) {                    // logits + Gumbel + wave argmax
        float l = f1b;
        #pragma unroll
        for (int kg = 0; kg < 8; ++kg) l += smem[512 + kg*64 + tid];
        l += -logf(1e-20f - logf(1e-20f + uval));
        float best = l; int idx = tid;
        #pragma unroll
        for (int off = 32; off >= 1; off >>= 1) {
          float ob = __shfl_xor(best, off);
          int   oi = __shfl_xor(idx,  off);
          if (ob > best || (ob == best && oi < idx)) { best = ob; idx = oi; }
        }
        if (tid == 0) {
          flg[0] = idx;
          flg[1] = (t < 64) ? t : jprev;
          jprev = idx;
        }
      }
      // ---- wait DEF + LATE blocks (g 64..223): 160 line-spaced flags ----
      if (tid < 160) {
        while (cohLoadI(&bar[1024 + (64 + tid)*32]) < t + 1) __builtin_amdgcn_s_sleep(1);
      }
      __syncthreads();
      const int jj = flg[0], ss = flg[1];
      float vA   = cohLoad(ocb + 512  + tid);
      float vB   = cohLoad(ocb + 1024 + tid);
      float vAW0 = cohLoad(ocb + 1536 + tid);
      float vAW1 = cohLoad(ocb + 2048 + tid);
      float vAW2 = cohLoad(ocb + 2560 + tid);
      float vBW0 = cohLoad(ocb + 3072 + tid);
      float vBW1 = cohLoad(ocb + 3584 + tid);
      float vBW2 = cohLoad(ocb + 4096 + tid);
      float hnp, w0, w1, w2;
      if (jj == ss) { hnp = vA; w0 = vAW0; w1 = vAW1; w2 = vAW2; }
      else {
        hnp = hnew_part[(size_t)(b*64 + jj)*512 + tid];
        const float* wpp = whh_part + (size_t)(b*64 + jj)*1536;
        w0 = wpp[tid]; w1 = wpp[512 + tid]; w2 = wpp[1024 + tid];
      }
      float h_new = hnp + vB + fc2bv;
      float wh_r = w0 + vBW0 + c0r;
      float wh_z = w1 + vBW1 + c0z;
      float wh_n = w2 + vBW2 + c0n;
      float r  = 1.f / (1.f + expf(-(p1r + wh_r)));
      float z  = 1.f / (1.f + expf(-(p1z + wh_z)));
      float nn = tanhf(p1n + r*wh_n);
      float h1 = (1.f - z)*nn + z*h_new;
      if (t >= lenb) h1 = hcur;
      hcur = h1;
      // publish h(t+1)+lu via sc1, b-major contiguous (coalesced full lines)
      float* hw = hTx_all + (size_t)(t + 1)*HTXS + (size_t)b*576;
      cohStore(&hw[tid], h1);
      if (tid < 64) {
        float un = (usage_r - 1.f) * (tid == jj ? 0.f : 1.f);
        usage_r = un;
        cohStore(&hw[512 + tid], 1.f / (1.f + expf(-un)));
      }
      smem[tid] = h1;                    // for out projection below
      __syncthreads();                   // drain sc1 stores
      if (tid == 0) cohStoreI(&bar[b*32], t + 1);
      // ---- off critical path: slot caches + output projection ----
      hnew_part[(size_t)(b*64 + ss)*512 + tid] = vA;
      float* wps = whh_part + (size_t)(b*64 + ss)*1536;
      wps[tid] = vAW0; wps[512 + tid] = vAW1; wps[1024 + tid] = vAW2;
      {
        int a = tid & 31, jg = tid >> 5;
        float sp = 0.f;
        #pragma unroll 8
        for (int jx = 0; jx < 32; ++jx)
          sp += smem[jg*32 + jx] * fc_w[(size_t)(jg*32 + jx)*32 + a];
        smem[512 + tid] = sp;
      }
      __syncthreads();
      if (tid < 32) {
        float s2 = fc_b[tid];
        #pragma unroll
        for (int jg = 0; jg < 16; ++jg) s2 += smem[512 + jg*32 + tid];
        out[(size_t)t32b*32 + tid] = s2;
      }
    }
  }
}

// ---------------------------------------------------------------------------
extern "C" void kernel_launch(void* const* d_in, const int* in_sizes, int n_in,
                              void* d_out, int out_size, void* d_ws, size_t ws_size,
                              hipStream_t stream)
{
  const float* x      = (const float*)d_in[0];
  const int*   length = (const int*)  d_in[1];
  const float* u_nois = (const float*)d_in[2];
  const float* W_ih   = (const float*)d_in[3];
  const float* W_hh   = (const float*)d_in[4];
  const float* bias   = (const float*)d_in[5];
  const float* W_im   = (const float*)d_in[6];
  const float* W_hm   = (const float*)d_in[7];
  const float* W_um   = (const float*)d_in[8];
  const float* fc1_w  = (const float*)d_in[9];
  const float* fc1_b  = (const float*)d_in[10];
  const float* fc2_w  = (const float*)d_in[11];
  const float* fc2_b  = (const float*)d_in[12];
  const float* fc_w   = (const float*)d_in[13];
  const float* fc_b   = (const float*)d_in[14];
  float* out = (float*)d_out;

  float* ws   = (float*)d_ws;
  int*   bar  = (int*)d_ws;
  float* hTx  = ws + OFF_HTX;
  float* oc   = ws + OFF_OC;
  float* hnew = ws + OFF_HNEW;
  float* whh  = ws + OFF_WHH;
  float* c0   = ws + OFF_C0;
  float* Wcat = ws + OFF_WCAT;
  unsigned short* Wb16 = (unsigned short*)(ws + OFF_WB16);
  float* P1   = ws + OFF_P1;
  float* P2   = ws + OFF_P2;

  // zero: flag words + hTx buffer 0 (h=0, lu=0); slot caches (mem=0)
  hipMemsetAsync(d_ws, 0, (size_t)(OFF_HTX + HTXS) * sizeof(float), stream);
  hipMemsetAsync(hnew, 0, (size_t)(32*64*512 + 32*64*1536) * sizeof(float), stream);

  setup_kernel<<<2115, 512, 0, stream>>>(W_hm, fc2_w, W_um, W_hh, bias, fc2_b,
                                         Wcat, c0);

  // M_A = fc2_A@W_hh -> Wcat cols 1536:3072 ; M_B = fc2_B@W_hh -> 3072:4608
  { dim3 g(4, 24);
    gemm_f32<<<g, 256, 0, stream>>>(fc2_w,                   W_hh, nullptr, Wcat + 1536,
                                    512, 1536, 512, 512, 1536, 4608);
    gemm_f32<<<g, 256, 0, stream>>>(fc2_w + (size_t)512*512, W_hh, nullptr, Wcat + 3072,
                                    512, 1536, 512, 512, 1536, 4608); }
  // bf16 compaction of the gate-path composite weights
  cvt_kernel<<<3072, 512, 0, stream>>>(Wcat, Wb16);
  // P1 = x@W_ih + bias_ih ; P2 = x@W_im
  { dim3 g(32, 24);
    gemm_f32<<<g, 256, 0, stream>>>(x, W_ih, bias, P1, 4096, 1536, 512, 512, 1536, 1536); }
  { dim3 g(32, 8);
    gemm_f32<<<g, 256, 0, stream>>>(x, W_im, nullptr, P2, 4096, 512, 512, 512, 512, 512); }

  persist_kernel<<<NBLK, NTHR, 0, stream>>>(P1, P2, Wcat, Wb16, oc, hTx, hnew,
                                            whh, c0, fc1_w, fc1_b, fc2_b,
                                            u_nois, length, fc_w, fc_b, out, bar);
}

// Round 12
// 1536.394 us; speedup vs baseline: 1.0707x; 1.0707x over previous
//
#include <hip/hip_runtime.h>
#include <hip/hip_bf16.h>
#include <math.h>

// T=128, B=32, D=512, H=512, N=64, A=32, TAU=1
#define NTHR  512
#define NBLK  256              // 32 BC blocks + 224 GEMM blocks (all CUs)
#define HTXS  18432            // hTx stride per t: 32 batches x 576 (b-major)

// ---- flag area (int offsets into d_ws), LINE-SPACED (r1/r6-proven best) ----
// hflag[b] = bar[b*32]           (BC b sc1-stores t+1; own 128B line)
// wflag[g] = bar[1024 + g*32]    (GEMM block g sc1-stores t+1)
//   g<64    "crit": cols [0,512)    fp32 K=576 (th path -> argmax)
//   64..127 "def":  cols [512,1536) fp32 K=576 (vA/vB path, argmax slack)
//   128..223 "late": cols [1536,4608) bf16 K=512, 64 cols/blk
// FINAL (r12 = r7, the session optimum at 1246us persist / 1544 total):
//   hTx b-major [129][32][576]: BC publish = 576 contiguous stores (~18
//   lines vs k-major's 512 partial lines; r4/r7-proven WRITE 181->117MB);
//   GEMM stages wave-private k-slices of the 16 b-major rows into LDS
//   [16][580] (stride 580 -> bq-row bank conflicts 2-way = free), inner
//   loop keeps r1's 4-batch x 2-col tile: 4 ds_read_b128 per 4k, weights
//   amortized x4 batches.
// Session ledger (why r7 is final):
//   r2  local-crit in BC        -> FETCH x6, LLC thrash (weight replication)
//   r4  b-major compute tiling  -> 1-batch/thread, VALU +60%
//   r5  no LDS staging          -> latency-bound, VALU 9.8%
//   r6  atomicAdd counters      -> RMW serialization > poll-storm savings
//   r8  fused tanh+fc1 in crit  -> work BEFORE producer flag extends chain
//   r9  crit 16->32 cols        -> argmax gate chain binds; regressed
//   r10 wait-split (3 polls)    -> +60us steady + 32ms outlier storms
//   r11 def K=576->512 isolated -> LESS work regressed: idle def blocks
//       over-poll the 32 h-flag lines (poll throttling lost); outlier too
#define OFF_HTX  8192                       // hTx_all: [129][32][576]
#define OFF_OC   (OFF_HTX + 129*HTXS)       // oc: [32][4608]
#define OFF_HNEW (OFF_OC + 32*4608)         // hnew_part: [32][64][512]
#define OFF_WHH  (OFF_HNEW + 32*64*512)     // whh_part: [32][64][1536]
#define OFF_C0   (OFF_WHH + 32*64*1536)     // c0: [1536]
#define OFF_WCAT (OFF_C0 + 1536)            // Wcat: [576][4608] fp32 row-major
#define OFF_WB16 (OFF_WCAT + 576*4608)      // Wb16: [512][3072] bf16 (ushort)
#define OFF_P1   (OFF_WB16 + 512*1536)      // P1: [4096][1536]
#define OFF_P2   (OFF_P1 + 4096*1536)       // P2: [4096][512]
// end ≈ 74.2 MB (< 76.5 MB known-good)

// sc1 (agent-scope): bypass per-XCD L2, coherent at LLC. Flags, oc, hTx
// writes are sc1; hTx READS are normal cached loads (rotating buffers).
__device__ __forceinline__ float cohLoad(const float* p) {
  return __hip_atomic_load(p, __ATOMIC_RELAXED, __HIP_MEMORY_SCOPE_AGENT);
}
__device__ __forceinline__ void cohStore(float* p, float v) {
  __hip_atomic_store(p, v, __ATOMIC_RELAXED, __HIP_MEMORY_SCOPE_AGENT);
}
__device__ __forceinline__ int cohLoadI(const int* p) {
  return __hip_atomic_load(p, __ATOMIC_RELAXED, __HIP_MEMORY_SCOPE_AGENT);
}
__device__ __forceinline__ void cohStoreI(int* p, int v) {
  __hip_atomic_store(p, v, __ATOMIC_RELAXED, __HIP_MEMORY_SCOPE_AGENT);
}
__device__ __forceinline__ float bf2f(unsigned short u) {
  return __uint_as_float(((unsigned int)u) << 16);
}

// ---------------------------------------------------------------------------
// Generic tiled fp32 GEMM (pre-pass only)
// ---------------------------------------------------------------------------
__global__ __launch_bounds__(256) void gemm_f32(
    const float* __restrict__ A, const float* __restrict__ B,
    const float* __restrict__ bias, float* __restrict__ C,
    int M, int N, int K, int lda, int ldb, int ldc)
{
  __shared__ float As[16][132];
  __shared__ float Bs[16][64];
  const int bm = blockIdx.x * 128, bn = blockIdx.y * 64;
  const int tid = threadIdx.x;
  const int tx = tid & 15, ty = tid >> 4;
  float acc[8][4];
  #pragma unroll
  for (int i = 0; i < 8; ++i)
    #pragma unroll
    for (int j = 0; j < 4; ++j) acc[i][j] = 0.f;

  for (int kt = 0; kt < K; kt += 16) {
    #pragma unroll
    for (int i = 0; i < 2; ++i) {
      int li = tid + i*256;
      int r = li >> 2, q = li & 3;
      float4 a4 = *(const float4*)(A + (size_t)(bm + r)*lda + kt + q*4);
      As[q*4+0][r] = a4.x; As[q*4+1][r] = a4.y;
      As[q*4+2][r] = a4.z; As[q*4+3][r] = a4.w;
    }
    {
      int k = tid >> 4, nq = tid & 15;
      *(float4*)(&Bs[k][nq*4]) = *(const float4*)(B + (size_t)(kt + k)*ldb + bn + nq*4);
    }
    __syncthreads();
    #pragma unroll
    for (int kk = 0; kk < 16; ++kk) {
      float av[8], bv[4];
      *(float4*)(av)   = *(const float4*)(&As[kk][ty*8]);
      *(float4*)(av+4) = *(const float4*)(&As[kk][ty*8+4]);
      *(float4*)(bv)   = *(const float4*)(&Bs[kk][tx*4]);
      #pragma unroll
      for (int i = 0; i < 8; ++i)
        #pragma unroll
        for (int j = 0; j < 4; ++j) acc[i][j] += av[i]*bv[j];
    }
    __syncthreads();
  }
  #pragma unroll
  for (int i = 0; i < 8; ++i) {
    int m = bm + ty*8 + i;
    #pragma unroll
    for (int j = 0; j < 4; ++j) {
      int n = bn + tx*4 + j;
      float v = acc[i][j];
      if (bias) v += bias[n];
      C[(size_t)m*ldc + n] = v;
    }
  }
}

// ---------------------------------------------------------------------------
// Setup: Wcat (row-major [576][4608]) static parts + c0.
// ---------------------------------------------------------------------------
__global__ __launch_bounds__(512) void setup_kernel(
    const float* __restrict__ W_hm, const float* __restrict__ fc2_w,
    const float* __restrict__ W_um, const float* __restrict__ W_hh,
    const float* __restrict__ bias, const float* __restrict__ fc2_b,
    float* __restrict__ Wcat, float* __restrict__ c0)
{
  const int idx = blockIdx.x * 512 + threadIdx.x;
  if (idx < 512*1536) {                       // rows 0:512, cols 0:1536
    int k = idx / 1536, c = idx % 1536;
    float v;
    if (c < 512)       v = W_hm[k*512 + c];
    else if (c < 1024) v = fc2_w[k*512 + (c-512)];
    else               v = fc2_w[(size_t)(512+k)*512 + (c-1024)];
    Wcat[(size_t)k*4608 + c] = v;
    return;
  }
  int i = idx - 512*1536;
  if (i < 64*4608) {                          // rows 512:576
    int k2 = i / 4608, c = i % 4608;
    Wcat[(size_t)(512+k2)*4608 + c] = (c < 512) ? W_um[k2*512 + c] : 0.f;
    return;
  }
  i -= 64*4608;
  if (i < 1536) {                             // c0 = fc2_b@W_hh + bias_hh
    float s = bias[1536 + i];
    for (int m = 0; m < 512; ++m) s += fc2_b[m] * W_hh[(size_t)m*1536 + i];
    c0[i] = s;
  }
}

// Wb16[k][3072] = bf16(Wcat[k][1536+c]), k<512 — runs after M_A/M_B GEMMs.
__global__ __launch_bounds__(512) void cvt_kernel(
    const float* __restrict__ Wcat, unsigned short* __restrict__ Wb16)
{
  const int idx = blockIdx.x * 512 + threadIdx.x;   // 512*3072
  const int k = idx / 3072, c = idx % 3072;
  __hip_bfloat16 h = __float2bfloat16(Wcat[(size_t)k*4608 + 1536 + c]);
  Wb16[idx] = *(unsigned short*)&h;
}

// ---------------------------------------------------------------------------
// Persistent scan. Blocks 0..31: BC (batch). Blocks 32..255: GEMM.
//   gb = bid-32, bg = gb&1 (batch half):
//     gb<64   crit: cols [cg*16,+16)        fp32 K=576 (16 segs x 36)
//     gb<128  def:  cols [512+cg*32,+32)    fp32 K=576 (8 segs x 72)
//     gb<224  late: cols [1536+cg*64,+64)   bf16 K=512 (8 segs x 64)
// LDS hxs[16][580] b-major; wave w stages its own k-slice (no stage bar).
// Thread tile (s, c, bq=4 batches): 4 ds_read_b128 per 4k, weights
// amortized x4 batches (r1 economics, r7-proven).
// ---------------------------------------------------------------------------
__global__ __launch_bounds__(NTHR, 1) void persist_kernel(
    const float* __restrict__ P1, const float* __restrict__ P2,
    const float* __restrict__ Wcat, const unsigned short* __restrict__ Wb16,
    float* __restrict__ oc, float* __restrict__ hTx_all,
    float* __restrict__ hnew_part, float* __restrict__ whh_part,
    const float* __restrict__ c0, const float* __restrict__ fc1_w,
    const float* __restrict__ fc1_b, const float* __restrict__ fc2_b,
    const float* __restrict__ u_noise, const int* __restrict__ length,
    const float* __restrict__ fc_w, const float* __restrict__ fc_b,
    float* __restrict__ out, int* __restrict__ bar)
{
  __shared__ float smem[13696]; // hxs 16x580=9280 + red (crit 16x272=4352)
  const int bid = blockIdx.x;
  const int tid = threadIdx.x;

  if (bid >= 32) {
    // ================= GEMM blocks =================
    const int gb = bid - 32;             // 0..223
    const int bg = gb & 1;               // batch half
    const int wv = tid >> 6, lane = tid & 63;
    const int bq = tid & 3;              // batch quad: rows bq*4..+3
    float* hxs = smem;                   // [16][580] b-major

    if (gb < 64) {
      // ---- crit: cols [cg*16,+16), fp32 K=576, 16 segs x 36 ----
      const int cg = gb >> 1;
      const int colbase = cg * 16;
      const int s = tid >> 5;            // 0..15 (wave covers 2 segs)
      const int c = (tid >> 2) & 7;      // 2 cols each
      const int kbase = s * 36;
      const float* wbase = Wcat + (size_t)kbase*4608 + colbase + c*2;
      float* red = smem + 9280;          // [16][272]
      for (int t = 0; t < 128; ++t) {
        if (tid < 16) {
          while (cohLoadI(&bar[(bg*16 + tid)*32]) < t) __builtin_amdgcn_s_sleep(1);
        }
        __syncthreads();
        {  // wave-private stage: k-slice [wv*72,+72) of 16 rows = 288 f4
          const float* hsrc = hTx_all + (size_t)t*HTXS + (size_t)(bg*16)*576 + wv*72;
          float* hdst = hxs + wv*72;
          for (int i = lane; i < 288; i += 64) {
            int bb = i / 18, q = i - bb*18;
            *(float4*)(hdst + bb*580 + q*4) = *(const float4*)(hsrc + bb*576 + q*4);
          }
        }
        float acc[4][2] = {{0.f,0.f},{0.f,0.f},{0.f,0.f},{0.f,0.f}};
        const float* hp = hxs + (bq*4)*580 + kbase;
        #pragma unroll 3
        for (int it = 0; it < 9; ++it) {
          float ha[4][4];
          *(float4*)(&ha[0][0]) = *(const float4*)(hp + 0*580 + it*4);
          *(float4*)(&ha[1][0]) = *(const float4*)(hp + 1*580 + it*4);
          *(float4*)(&ha[2][0]) = *(const float4*)(hp + 2*580 + it*4);
          *(float4*)(&ha[3][0]) = *(const float4*)(hp + 3*580 + it*4);
          const float* wp = wbase + (size_t)(it*4)*4608;
          #pragma unroll
          for (int kk = 0; kk < 4; ++kk) {
            float w0 = wp[0], w1 = wp[1]; wp += 4608;
            #pragma unroll
            for (int j = 0; j < 4; ++j) {
              acc[j][0] += ha[j][kk]*w0;
              acc[j][1] += ha[j][kk]*w1;
            }
          }
        }
        {
          float* rp = red + s*272 + (bq*4)*16 + c*2;
          #pragma unroll
          for (int j = 0; j < 4; ++j)
            *(float2*)(rp + j*16) = make_float2(acc[j][0], acc[j][1]);
        }
        __syncthreads();
        if (tid < 256) {                 // 16b x 16c outputs
          float ssum = 0.f;
          #pragma unroll
          for (int w = 0; w < 16; ++w) ssum += red[w*272 + tid];
          int b16 = tid >> 4, cc = tid & 15;
          cohStore(&oc[(size_t)(bg*16 + b16)*4608 + colbase + cc], ssum);
        }
        __syncthreads();                 // drain sc1 stores
        if (tid == 0) cohStoreI(&bar[1024 + gb*32], t + 1);
      }
    } else if (gb < 128) {
      // ---- def: cols [512+cg*32,+32), fp32 K=576, 8 segs x 72 ----
      const int cg = (gb - 64) >> 1;
      const int colbase = 512 + cg * 32;
      const int s = tid >> 6;            // 0..7 (= wave)
      const int c = (tid >> 2) & 15;     // 2 cols each
      const int kbase = s * 72;
      const float* wbase = Wcat + (size_t)kbase*4608 + colbase + c*2;
      float* red = smem + 9280;          // [8][520]
      for (int t = 0; t < 128; ++t) {
        if (tid < 16) {
          while (cohLoadI(&bar[(bg*16 + tid)*32]) < t) __builtin_amdgcn_s_sleep(1);
        }
        __syncthreads();
        {  // wave-private stage: k-slice [wv*72,+72) of 16 rows
          const float* hsrc = hTx_all + (size_t)t*HTXS + (size_t)(bg*16)*576 + wv*72;
          float* hdst = hxs + wv*72;
          for (int i = lane; i < 288; i += 64) {
            int bb = i / 18, q = i - bb*18;
            *(float4*)(hdst + bb*580 + q*4) = *(const float4*)(hsrc + bb*576 + q*4);
          }
        }
        float acc[4][2] = {{0.f,0.f},{0.f,0.f},{0.f,0.f},{0.f,0.f}};
        const float* hp = hxs + (bq*4)*580 + kbase;
        #pragma unroll 3
        for (int it = 0; it < 18; ++it) {
          float ha[4][4];
          *(float4*)(&ha[0][0]) = *(const float4*)(hp + 0*580 + it*4);
          *(float4*)(&ha[1][0]) = *(const float4*)(hp + 1*580 + it*4);
          *(float4*)(&ha[2][0]) = *(const float4*)(hp + 2*580 + it*4);
          *(float4*)(&ha[3][0]) = *(const float4*)(hp + 3*580 + it*4);
          const float* wp = wbase + (size_t)(it*4)*4608;
          #pragma unroll
          for (int kk = 0; kk < 4; ++kk) {
            float w0 = wp[0], w1 = wp[1]; wp += 4608;
            #pragma unroll
            for (int j = 0; j < 4; ++j) {
              acc[j][0] += ha[j][kk]*w0;
              acc[j][1] += ha[j][kk]*w1;
            }
          }
        }
        {
          float* rp = red + s*520 + (bq*4)*32 + c*2;
          #pragma unroll
          for (int j = 0; j < 4; ++j)
            *(float2*)(rp + j*32) = make_float2(acc[j][0], acc[j][1]);
        }
        __syncthreads();
        {                                 // 16b x 32c, one per thread
          float ssum = 0.f;
          #pragma unroll
          for (int w = 0; w < 8; ++w) ssum += red[w*520 + tid];
          int b16 = tid >> 5, cc = tid & 31;
          cohStore(&oc[(size_t)(bg*16 + b16)*4608 + colbase + cc], ssum);
        }
        __syncthreads();                 // drain sc1 stores
        if (tid == 0) cohStoreI(&bar[1024 + gb*32], t + 1);
      }
    } else {
      // ---- late: cols [1536+cg*64,+64), bf16 K=512, 8 segs x 64 ----
      const int cg = (gb - 128) >> 1;
      const int colbase = 1536 + cg * 64;
      const int s = tid >> 6;            // 0..7 (= wave)
      const int c = (tid >> 2) & 15;     // 4 cols each
      const int kbase = s * 64;
      const unsigned short* wbase = Wb16 + (size_t)kbase*3072 + (colbase - 1536) + c*4;
      float* red = smem;                 // [8][1024] ALIASES hxs (barrier-fenced)
      for (int t = 0; t < 128; ++t) {
        if (tid < 16) {
          while (cohLoadI(&bar[(bg*16 + tid)*32]) < t) __builtin_amdgcn_s_sleep(1);
        }
        __syncthreads();
        {  // wave-private stage: k-slice [wv*64,+64) of 16 rows = 256 f4
          const float* hsrc = hTx_all + (size_t)t*HTXS + (size_t)(bg*16)*576 + wv*64;
          float* hdst = hxs + wv*64;
          for (int i = lane; i < 256; i += 64) {
            int bb = i >> 4, q = i & 15;
            *(float4*)(hdst + bb*580 + q*4) = *(const float4*)(hsrc + bb*576 + q*4);
          }
        }
        float acc[4][4] = {{0.f,0.f,0.f,0.f},{0.f,0.f,0.f,0.f},
                           {0.f,0.f,0.f,0.f},{0.f,0.f,0.f,0.f}};
        const float* hp = hxs + (bq*4)*580 + kbase;
        #pragma unroll 2
        for (int it = 0; it < 16; ++it) {
          float ha[4][4];
          *(float4*)(&ha[0][0]) = *(const float4*)(hp + 0*580 + it*4);
          *(float4*)(&ha[1][0]) = *(const float4*)(hp + 1*580 + it*4);
          *(float4*)(&ha[2][0]) = *(const float4*)(hp + 2*580 + it*4);
          *(float4*)(&ha[3][0]) = *(const float4*)(hp + 3*580 + it*4);
          #pragma unroll
          for (int kk = 0; kk < 4; ++kk) {
            const ushort4 u4 = *(const ushort4*)(wbase + (size_t)(it*4 + kk)*3072);
            float w0 = bf2f(u4.x), w1 = bf2f(u4.y), w2 = bf2f(u4.z), w3 = bf2f(u4.w);
            #pragma unroll
            for (int j = 0; j < 4; ++j) {
              float f = ha[j][kk];
              acc[j][0] += f*w0; acc[j][1] += f*w1;
              acc[j][2] += f*w2; acc[j][3] += f*w3;
            }
          }
        }
        __syncthreads();                 // all computes done before alias write
        {
          float* rp = red + s*1024 + (bq*4)*64 + c*4;
          #pragma unroll
          for (int j = 0; j < 4; ++j)
            *(float4*)(rp + j*64) = make_float4(acc[j][0], acc[j][1], acc[j][2], acc[j][3]);
        }
        __syncthreads();
        for (int i = tid; i < 1024; i += NTHR) {  // 16b x 64c
          float ssum = 0.f;
          #pragma unroll
          for (int w = 0; w < 8; ++w) ssum += red[w*1024 + i];
          int b16 = i >> 6, cc = i & 63;
          cohStore(&oc[(size_t)(bg*16 + b16)*4608 + colbase + cc], ssum);
        }
        __syncthreads();                 // drain sc1 stores
        if (tid == 0) cohStoreI(&bar[1024 + gb*32], t + 1);
      }
    }
  } else {
    // ================= BC block: batch b =================
    const int b = bid;
    const int lenb = length[b];
    float hcur = 0.f;
    float usage_r = -99999.f;            // valid for tid<64
    int jprev = 0;                       // thread-0 only
    int* flg = (int*)(smem + 1100);
    const float c0r = c0[tid], c0z = c0[512 + tid], c0n = c0[1024 + tid];
    const float fc2bv = fc2_b[tid];
    const float f1b = (tid < 64) ? fc1_b[tid] : 0.f;
    const int n_ = tid & 63, kg_ = tid >> 6;
    const float* fw = fc1_w + (size_t)kg_*64*64 + n_;

    for (int t = 0; t < 128; ++t) {
      const int t32b = t*32 + b;
      // prefetch step inputs (independent of flags)
      const float* p1p = P1 + (size_t)t32b*1536;
      float p1r = p1p[tid], p1z = p1p[512 + tid], p1n = p1p[1024 + tid];
      float p2v = P2[(size_t)t32b*512 + tid];
      float uval = (tid < 64) ? u_noise[(size_t)t32b*64 + tid] : 0.f;
      // ---- wait CRIT blocks (g 0..63): argmax chain ----
      if (tid < 64) {
        while (cohLoadI(&bar[1024 + tid*32]) < t + 1) __builtin_amdgcn_s_sleep(1);
      }
      __syncthreads();
      const float* ocb = oc + (size_t)b*4608;
      float oct = cohLoad(ocb + tid);
      smem[tid] = tanhf(p2v + oct);      // th
      __syncthreads();
      {                                  // fc1 partial dots
        float sdot = 0.f;
        #pragma unroll 8
        for (int k = 0; k < 64; ++k) sdot += smem[kg_*64 + k] * fw[(size_t)k*64];
        smem[512 + tid] = sdot;
      }
      __syncthreads();
      if (tid < 64) {                    // logits + Gumbel + wave argmax
        float l = f1b;
        #pragma unroll
        for (int kg = 0; kg < 8; ++kg) l += smem[512 + kg*64 + tid];
        l += -logf(1e-20f - logf(1e-20f + uval));
        float best = l; int idx = tid;
        #pragma unroll
        for (int off = 32; off >= 1; off >>= 1) {
          float ob = __shfl_xor(best, off);
          int   oi = __shfl_xor(idx,  off);
          if (ob > best || (ob == best && oi < idx)) { best = ob; idx = oi; }
        }
        if (tid == 0) {
          flg[0] = idx;
          flg[1] = (t < 64) ? t : jprev;
          jprev = idx;
        }
      }
      // ---- wait DEF + LATE blocks (g 64..223): 160 line-spaced flags ----
      if (tid < 160) {
        while (cohLoadI(&bar[1024 + (64 + tid)*32]) < t + 1) __builtin_amdgcn_s_sleep(1);
      }
      __syncthreads();
      const int jj = flg[0], ss = flg[1];
      float vA   = cohLoad(ocb + 512  + tid);
      float vB   = cohLoad(ocb + 1024 + tid);
      float vAW0 = cohLoad(ocb + 1536 + tid);
      float vAW1 = cohLoad(ocb + 2048 + tid);
      float vAW2 = cohLoad(ocb + 2560 + tid);
      float vBW0 = cohLoad(ocb + 3072 + tid);
      float vBW1 = cohLoad(ocb + 3584 + tid);
      float vBW2 = cohLoad(ocb + 4096 + tid);
      float hnp, w0, w1, w2;
      if (jj == ss) { hnp = vA; w0 = vAW0; w1 = vAW1; w2 = vAW2; }
      else {
        hnp = hnew_part[(size_t)(b*64 + jj)*512 + tid];
        const float* wpp = whh_part + (size_t)(b*64 + jj)*1536;
        w0 = wpp[tid]; w1 = wpp[512 + tid]; w2 = wpp[1024 + tid];
      }
      float h_new = hnp + vB + fc2bv;
      float wh_r = w0 + vBW0 + c0r;
      float wh_z = w1 + vBW1 + c0z;
      float wh_n = w2 + vBW2 + c0n;
      float r  = 1.f / (1.f + expf(-(p1r + wh_r)));
      float z  = 1.f / (1.f + expf(-(p1z + wh_z)));
      float nn = tanhf(p1n + r*wh_n);
      float h1 = (1.f - z)*nn + z*h_new;
      if (t >= lenb) h1 = hcur;
      hcur = h1;
      // publish h(t+1)+lu via sc1, b-major contiguous (coalesced full lines)
      float* hw = hTx_all + (size_t)(t + 1)*HTXS + (size_t)b*576;
      cohStore(&hw[tid], h1);
      if (tid < 64) {
        float un = (usage_r - 1.f) * (tid == jj ? 0.f : 1.f);
        usage_r = un;
        cohStore(&hw[512 + tid], 1.f / (1.f + expf(-un)));
      }
      smem[tid] = h1;                    // for out projection below
      __syncthreads();                   // drain sc1 stores
      if (tid == 0) cohStoreI(&bar[b*32], t + 1);
      // ---- off critical path: slot caches + output projection ----
      hnew_part[(size_t)(b*64 + ss)*512 + tid] = vA;
      float* wps = whh_part + (size_t)(b*64 + ss)*1536;
      wps[tid] = vAW0; wps[512 + tid] = vAW1; wps[1024 + tid] = vAW2;
      {
        int a = tid & 31, jg = tid >> 5;
        float sp = 0.f;
        #pragma unroll 8
        for (int jx = 0; jx < 32; ++jx)
          sp += smem[jg*32 + jx] * fc_w[(size_t)(jg*32 + jx)*32 + a];
        smem[512 + tid] = sp;
      }
      __syncthreads();
      if (tid < 32) {
        float s2 = fc_b[tid];
        #pragma unroll
        for (int jg = 0; jg < 16; ++jg) s2 += smem[512 + jg*32 + tid];
        out[(size_t)t32b*32 + tid] = s2;
      }
    }
  }
}

// ---------------------------------------------------------------------------
extern "C" void kernel_launch(void* const* d_in, const int* in_sizes, int n_in,
                              void* d_out, int out_size, void* d_ws, size_t ws_size,
                              hipStream_t stream)
{
  const float* x      = (const float*)d_in[0];
  const int*   length = (const int*)  d_in[1];
  const float* u_nois = (const float*)d_in[2];
  const float* W_ih   = (const float*)d_in[3];
  const float* W_hh   = (const float*)d_in[4];
  const float* bias   = (const float*)d_in[5];
  const float* W_im   = (const float*)d_in[6];
  const float* W_hm   = (const float*)d_in[7];
  const float* W_um   = (const float*)d_in[8];
  const float* fc1_w  = (const float*)d_in[9];
  const float* fc1_b  = (const float*)d_in[10];
  const float* fc2_w  = (const float*)d_in[11];
  const float* fc2_b  = (const float*)d_in[12];
  const float* fc_w   = (const float*)d_in[13];
  const float* fc_b   = (const float*)d_in[14];
  float* out = (float*)d_out;

  float* ws   = (float*)d_ws;
  int*   bar  = (int*)d_ws;
  float* hTx  = ws + OFF_HTX;
  float* oc   = ws + OFF_OC;
  float* hnew = ws + OFF_HNEW;
  float* whh  = ws + OFF_WHH;
  float* c0   = ws + OFF_C0;
  float* Wcat = ws + OFF_WCAT;
  unsigned short* Wb16 = (unsigned short*)(ws + OFF_WB16);
  float* P1   = ws + OFF_P1;
  float* P2   = ws + OFF_P2;

  // zero: flag words + hTx buffer 0 (h=0, lu=0); slot caches (mem=0)
  hipMemsetAsync(d_ws, 0, (size_t)(OFF_HTX + HTXS) * sizeof(float), stream);
  hipMemsetAsync(hnew, 0, (size_t)(32*64*512 + 32*64*1536) * sizeof(float), stream);

  setup_kernel<<<2115, 512, 0, stream>>>(W_hm, fc2_w, W_um, W_hh, bias, fc2_b,
                                         Wcat, c0);

  // M_A = fc2_A@W_hh -> Wcat cols 1536:3072 ; M_B = fc2_B@W_hh -> 3072:4608
  { dim3 g(4, 24);
    gemm_f32<<<g, 256, 0, stream>>>(fc2_w,                   W_hh, nullptr, Wcat + 1536,
                                    512, 1536, 512, 512, 1536, 4608);
    gemm_f32<<<g, 256, 0, stream>>>(fc2_w + (size_t)512*512, W_hh, nullptr, Wcat + 3072,
                                    512, 1536, 512, 512, 1536, 4608); }
  // bf16 compaction of the gate-path composite weights
  cvt_kernel<<<3072, 512, 0, stream>>>(Wcat, Wb16);
  // P1 = x@W_ih + bias_ih ; P2 = x@W_im
  { dim3 g(32, 24);
    gemm_f32<<<g, 256, 0, stream>>>(x, W_ih, bias, P1, 4096, 1536, 512, 512, 1536, 1536); }
  { dim3 g(32, 8);
    gemm_f32<<<g, 256, 0, stream>>>(x, W_im, nullptr, P2, 4096, 512, 512, 512, 512, 512); }

  persist_kernel<<<NBLK, NTHR, 0, stream>>>(P1, P2, Wcat, Wb16, oc, hTx, hnew,
                                            whh, c0, fc1_w, fc1_b, fc2_b,
                                            u_nois, length, fc_w, fc_b, out, bar);
}